// Round 1
// baseline (753.997 us; speedup 1.0000x reference)
//
#include <hip/hip_runtime.h>
#include <hip/hip_bf16.h>
#include <cstdint>
#include <cstddef>

#define N_NODES 8192
#define NE      131072
#define NR      4

__device__ __forceinline__ float sigmoidf_(float x) {
  return 1.0f / (1.0f + __expf(-x));
}

// ---------------- embedding concat: x_ (N,384) ----------------
__global__ void k_embed(const int* __restrict__ xi,
                        const float* __restrict__ e0, const float* __restrict__ e1,
                        const float* __restrict__ e2, const float* __restrict__ e3,
                        const float* __restrict__ e4, const float* __restrict__ e5,
                        float* __restrict__ xo) {
  int n = blockIdx.x;
  int c = threadIdx.x;            // 0..383, wave-uniform table index (c>>6)
  int i = c >> 6, d = c & 63;
  const float* t;
  switch (i) {
    case 0: t = e0; break; case 1: t = e1; break; case 2: t = e2; break;
    case 3: t = e3; break; case 4: t = e4; break; default: t = e5; break;
  }
  int idx = xi[n * 6 + i];
  xo[(size_t)n * 384 + c] = t[(size_t)idx * 64 + d];
}

// ---------------- pack [root | W0 | W1 | W2 | W3] -> Bcat (K,1280) ----------------
__global__ void k_pack(const float* __restrict__ root, const float* __restrict__ W,
                       float* __restrict__ Bc, int K) {
  int k = blockIdx.x, seg = blockIdx.y, c = threadIdx.x;
  float v = (seg == 0) ? root[(size_t)k * 256 + c]
                       : W[((size_t)(seg - 1) * K + k) * 256 + c];
  Bc[(size_t)k * 1280 + seg * 256 + c] = v;
}

// ---------------- f32 tiled GEMM: C(M,Nc) = A(M,K) @ B(K,Nc), row-major ----------------
// 128x128 tile, KT=16, 256 threads, 8x8 per thread
__global__ __launch_bounds__(256) void k_gemm(const float* __restrict__ A,
                                              const float* __restrict__ B,
                                              float* __restrict__ C,
                                              int M, int K, int Nc) {
  __shared__ float As[16][128];
  __shared__ float Bs[16][128];
  const int bm = blockIdx.y * 128, bn = blockIdx.x * 128;
  const int tid = threadIdx.x;
  const int tx = tid & 15, ty = tid >> 4;
  const int ra = tid >> 1, ka = (tid & 1) * 8;   // A-tile load: row, k-offset
  const int kb = tid >> 5, nb = (tid & 31) * 4;  // B-tile load
  float acc[8][8] = {};
  for (int k0 = 0; k0 < K; k0 += 16) {
    const float* ap = A + (size_t)(bm + ra) * K + k0 + ka;
    float4 a0 = *(const float4*)ap;
    float4 a1 = *(const float4*)(ap + 4);
    As[ka + 0][ra] = a0.x; As[ka + 1][ra] = a0.y; As[ka + 2][ra] = a0.z; As[ka + 3][ra] = a0.w;
    As[ka + 4][ra] = a1.x; As[ka + 5][ra] = a1.y; As[ka + 6][ra] = a1.z; As[ka + 7][ra] = a1.w;
    const float* bp = B + (size_t)(k0 + kb) * Nc + bn + nb;
    *(float4*)&Bs[kb][nb]     = *(const float4*)bp;
    *(float4*)&Bs[kb + 8][nb] = *(const float4*)(bp + (size_t)8 * Nc);
    __syncthreads();
#pragma unroll
    for (int k = 0; k < 16; ++k) {
      float av[8], bv[8];
      *(float4*)&av[0] = *(const float4*)&As[k][ty * 8];
      *(float4*)&av[4] = *(const float4*)&As[k][ty * 8 + 4];
      *(float4*)&bv[0] = *(const float4*)&Bs[k][tx * 8];
      *(float4*)&bv[4] = *(const float4*)&Bs[k][tx * 8 + 4];
#pragma unroll
      for (int i = 0; i < 8; ++i)
#pragma unroll
        for (int j = 0; j < 8; ++j)
          acc[i][j] = fmaf(av[i], bv[j], acc[i][j]);
    }
    __syncthreads();
  }
#pragma unroll
  for (int i = 0; i < 8; ++i) {
    float* cp = C + (size_t)(bm + ty * 8 + i) * Nc + bn + tx * 8;
    *(float4*)cp       = *(float4*)&acc[i][0];
    *(float4*)(cp + 4) = *(float4*)&acc[i][4];
  }
}

// ---------------- zero (float4 grid-stride) ----------------
__global__ void k_zerof4(float4* __restrict__ p, size_t n4) {
  size_t i = (size_t)blockIdx.x * blockDim.x + threadIdx.x;
  size_t stride = (size_t)gridDim.x * blockDim.x;
  float4 z = make_float4(0.f, 0.f, 0.f, 0.f);
  for (; i < n4; i += stride) p[i] = z;
}

// ---------------- edge aggregation (atomics), 16 edges per block ----------------
__global__ __launch_bounds__(256) void k_edges(const float* __restrict__ hall,
                                               const int* __restrict__ src,
                                               const int* __restrict__ dst,
                                               const int* __restrict__ et,
                                               float* __restrict__ s,
                                               float* __restrict__ cnt) {
  int c = threadIdx.x;
  int e0 = blockIdx.x * 16;
#pragma unroll 1
  for (int e = e0; e < e0 + 16; ++e) {
    int sN = src[e], dN = dst[e], r = et[e];
    float v = hall[(size_t)sN * 1280 + 256 + (size_t)r * 256 + c];
    atomicAdd(&s[((size_t)r * N_NODES + dN) * 256 + c], v);
    if (c == 0) atomicAdd(&cnt[(size_t)r * N_NODES + dN], 1.0f);
  }
}

// ---------------- combine layer 1 -> h1 = sigmoid(root + b + sum_r s_r/max(c_r,1)) ----------------
__global__ void k_combine1(const float* __restrict__ hall, const float* __restrict__ bias,
                           const float* __restrict__ s, const float* __restrict__ cnt,
                           float* __restrict__ h1o) {
  int n = blockIdx.x, c = threadIdx.x;
  float v = hall[(size_t)n * 1280 + c] + bias[c];
#pragma unroll
  for (int r = 0; r < NR; ++r) {
    float cn = cnt[(size_t)r * N_NODES + n];
    v += s[((size_t)r * N_NODES + n) * 256 + c] / fmaxf(cn, 1.0f);
  }
  h1o[(size_t)n * 256 + c] = sigmoidf_(v);
}

// ---------------- combine layer 2 -> mu, logvar directly to d_out ----------------
__global__ void k_combine2(const float* __restrict__ hall, const float* __restrict__ bias,
                           const float* __restrict__ s, const float* __restrict__ cnt,
                           float* __restrict__ muo, float* __restrict__ lvo) {
  int n = blockIdx.x, c = threadIdx.x;
  float v = hall[(size_t)n * 1280 + c] + bias[c];
#pragma unroll
  for (int r = 0; r < NR; ++r) {
    float cn = cnt[(size_t)r * N_NODES + n];
    v += s[((size_t)r * N_NODES + n) * 256 + c] / fmaxf(cn, 1.0f);
  }
  float sg = sigmoidf_(v);
  if (c < 128) muo[(size_t)n * 128 + c] = sg;
  else         lvo[(size_t)n * 128 + (c - 128)] = sg;
}

// ---------------- JAX threefry2x32 (partitionable) -> eps -> Z ----------------
__device__ __forceinline__ float bits_to_normal(unsigned bits) {
  float f = __uint_as_float((bits >> 9) | 0x3f800000u) - 1.0f;  // [0,1)
  const float lo = -0.99999994f;  // nextafter(-1,0) f32
  // maxval-minval rounds to exactly 2.0f in f32; f*2 is exact -> u bit-exact vs XLA
  float u = __fadd_rn(__fmul_rn(f, 2.0f), lo);
  u = fmaxf(lo, u);
  float w = -log1pf(-u * u);
  float p;
  if (w < 5.0f) {
    w = w - 2.5f;
    p = 2.81022636e-08f;
    p = fmaf(p, w, 3.43273939e-07f);
    p = fmaf(p, w, -3.5233877e-06f);
    p = fmaf(p, w, -4.39150654e-06f);
    p = fmaf(p, w, 0.00021858087f);
    p = fmaf(p, w, -0.00125372503f);
    p = fmaf(p, w, -0.00417768164f);
    p = fmaf(p, w, 0.246640727f);
    p = fmaf(p, w, 1.50140941f);
  } else {
    w = sqrtf(w) - 3.0f;
    p = -0.000200214257f;
    p = fmaf(p, w, 0.000100950558f);
    p = fmaf(p, w, 0.00134934322f);
    p = fmaf(p, w, -0.00367342844f);
    p = fmaf(p, w, 0.00573950773f);
    p = fmaf(p, w, -0.0076224613f);
    p = fmaf(p, w, 0.00943887047f);
    p = fmaf(p, w, 1.00167406f);
    p = fmaf(p, w, 2.83297682f);
  }
  return 1.41421356f * (p * u);   // sqrt(2) * erfinv(u)
}

__global__ void k_z(const float* __restrict__ mu, const float* __restrict__ lv,
                    float* __restrict__ Z) {
  unsigned j = blockIdx.x * 256 + threadIdx.x;  // 0 .. N*128-1
  const unsigned ks0 = 0u, ks1 = 42u, ks2 = 0x1BD11BDAu ^ 0u ^ 42u;
  unsigned x0 = 0u + ks0;   // hi 32 bits of 64-bit counter (all zero here)
  unsigned x1 = j + ks1;    // lo 32 bits
#define RND(r) { x0 += x1; x1 = (x1 << r) | (x1 >> (32 - r)); x1 ^= x0; }
  RND(13) RND(15) RND(26) RND(6)  x0 += ks1; x1 += ks2 + 1u;
  RND(17) RND(29) RND(16) RND(24) x0 += ks2; x1 += ks0 + 2u;
  RND(13) RND(15) RND(26) RND(6)  x0 += ks0; x1 += ks1 + 3u;
  RND(17) RND(29) RND(16) RND(24) x0 += ks1; x1 += ks2 + 4u;
  RND(13) RND(15) RND(26) RND(6)  x0 += ks2; x1 += ks0 + 5u;
#undef RND
  unsigned bits = x0 ^ x1;        // partitionable 32-bit path
  float e = bits_to_normal(bits);
  Z[j] = fmaf(e, __expf(0.5f * lv[j]), mu[j]);
}

// ---------------- A_hat = sigmoid(Z @ Z^T), 128x128 tile ----------------
__global__ __launch_bounds__(256) void k_ahat(const float* __restrict__ Z,
                                              float* __restrict__ out) {
  __shared__ float As[16][128];
  __shared__ float Bs[16][128];
  const int bi = blockIdx.y * 128, bj = blockIdx.x * 128;
  const int tid = threadIdx.x;
  const int tx = tid & 15, ty = tid >> 4;
  const int rr = tid >> 1, kc = (tid & 1) * 8;
  float acc[8][8] = {};
  for (int k0 = 0; k0 < 128; k0 += 16) {
    const float* ap = Z + (size_t)(bi + rr) * 128 + k0 + kc;
    float4 a0 = *(const float4*)ap;
    float4 a1 = *(const float4*)(ap + 4);
    As[kc + 0][rr] = a0.x; As[kc + 1][rr] = a0.y; As[kc + 2][rr] = a0.z; As[kc + 3][rr] = a0.w;
    As[kc + 4][rr] = a1.x; As[kc + 5][rr] = a1.y; As[kc + 6][rr] = a1.z; As[kc + 7][rr] = a1.w;
    const float* bp = Z + (size_t)(bj + rr) * 128 + k0 + kc;
    float4 b0 = *(const float4*)bp;
    float4 b1 = *(const float4*)(bp + 4);
    Bs[kc + 0][rr] = b0.x; Bs[kc + 1][rr] = b0.y; Bs[kc + 2][rr] = b0.z; Bs[kc + 3][rr] = b0.w;
    Bs[kc + 4][rr] = b1.x; Bs[kc + 5][rr] = b1.y; Bs[kc + 6][rr] = b1.z; Bs[kc + 7][rr] = b1.w;
    __syncthreads();
#pragma unroll
    for (int k = 0; k < 16; ++k) {
      float av[8], bv[8];
      *(float4*)&av[0] = *(const float4*)&As[k][ty * 8];
      *(float4*)&av[4] = *(const float4*)&As[k][ty * 8 + 4];
      *(float4*)&bv[0] = *(const float4*)&Bs[k][tx * 8];
      *(float4*)&bv[4] = *(const float4*)&Bs[k][tx * 8 + 4];
#pragma unroll
      for (int i = 0; i < 8; ++i)
#pragma unroll
        for (int j = 0; j < 8; ++j)
          acc[i][j] = fmaf(av[i], bv[j], acc[i][j]);
    }
    __syncthreads();
  }
#pragma unroll
  for (int i = 0; i < 8; ++i) {
    float r0[8];
#pragma unroll
    for (int j = 0; j < 8; ++j) r0[j] = sigmoidf_(acc[i][j]);
    float* cp = out + (size_t)(bi + ty * 8 + i) * N_NODES + bj + tx * 8;
    *(float4*)cp       = *(float4*)&r0[0];
    *(float4*)(cp + 4) = *(float4*)&r0[4];
  }
}

// ---------------- A scatter ----------------
__global__ void k_scatterA(const int* __restrict__ src, const int* __restrict__ dst,
                           float* __restrict__ A) {
  int e = blockIdx.x * 256 + threadIdx.x;
  if (e < NE) A[(size_t)src[e] * N_NODES + dst[e]] = 1.0f;
}

extern "C" void kernel_launch(void* const* d_in, const int* in_sizes, int n_in,
                              void* d_out, int out_size, void* d_ws, size_t ws_size,
                              hipStream_t stream) {
  const int* x    = (const int*)d_in[0];
  const int* ei   = (const int*)d_in[1];
  const int* src  = ei;
  const int* dst  = ei + NE;
  const int* et   = (const int*)d_in[2];
  const float* e0 = (const float*)d_in[3];
  const float* e1 = (const float*)d_in[4];
  const float* e2 = (const float*)d_in[5];
  const float* e3 = (const float*)d_in[6];
  const float* e4 = (const float*)d_in[7];
  const float* e5 = (const float*)d_in[8];
  const float* W1 = (const float*)d_in[9];
  const float* r1 = (const float*)d_in[10];
  const float* b1 = (const float*)d_in[11];
  const float* W2 = (const float*)d_in[12];
  const float* r2 = (const float*)d_in[13];
  const float* b2 = (const float*)d_in[14];

  float* out  = (float*)d_out;
  float* A    = out;                                    // N*N
  float* Ahat = out + (size_t)N_NODES * N_NODES;        // N*N
  float* muo  = Ahat + (size_t)N_NODES * N_NODES;       // N*128
  float* lvo  = muo + (size_t)N_NODES * 128;            // N*128

  float* ws0  = (float*)d_ws;
  float* regA = ws0;                       // x_ (N*384) -> h1 (N*256) -> Z (N*128)
  float* Bc   = regA + (size_t)8192 * 384;
  float* hall = Bc + (size_t)5 * 384 * 256;
  float* sbuf = hall + (size_t)8192 * 1280;
  float* cnt  = sbuf + (size_t)4 * 8192 * 256;
  float* x_   = regA;
  float* h1   = regA;
  float* Zb   = regA;

  size_t s_n4 = ((size_t)4 * 8192 * 256 + 4 * 8192) / 4;

  // layer 1
  k_embed<<<8192, 384, 0, stream>>>(x, e0, e1, e2, e3, e4, e5, x_);
  k_pack<<<dim3(384, 5), 256, 0, stream>>>(r1, W1, Bc, 384);
  k_gemm<<<dim3(10, 64), 256, 0, stream>>>(x_, Bc, hall, 8192, 384, 1280);
  k_zerof4<<<2048, 256, 0, stream>>>((float4*)sbuf, s_n4);
  k_edges<<<NE / 16, 256, 0, stream>>>(hall, src, dst, et, sbuf, cnt);
  k_combine1<<<8192, 256, 0, stream>>>(hall, b1, sbuf, cnt, h1);

  // layer 2
  k_pack<<<dim3(256, 5), 256, 0, stream>>>(r2, W2, Bc, 256);
  k_gemm<<<dim3(10, 64), 256, 0, stream>>>(h1, Bc, hall, 8192, 256, 1280);
  k_zerof4<<<2048, 256, 0, stream>>>((float4*)sbuf, s_n4);
  k_edges<<<NE / 16, 256, 0, stream>>>(hall, src, dst, et, sbuf, cnt);
  k_combine2<<<8192, 256, 0, stream>>>(hall, b2, sbuf, cnt, muo, lvo);

  // reparametrize (JAX threefry) -> Z
  k_z<<<4096, 256, 0, stream>>>(muo, lvo, Zb);

  // A = scatter(1.0)
  k_zerof4<<<8192, 256, 0, stream>>>((float4*)A, (size_t)N_NODES * N_NODES / 4);
  k_scatterA<<<NE / 256, 256, 0, stream>>>(src, dst, A);

  // A_hat = sigmoid(Z @ Z^T)
  k_ahat<<<dim3(64, 64), 256, 0, stream>>>(Zb, Ahat);
}

// Round 2
// 498.570 us; speedup vs baseline: 1.5123x; 1.5123x over previous
//
#include <hip/hip_runtime.h>
#include <hip/hip_bf16.h>
#include <cstdint>
#include <cstddef>

#define N_NODES 8192
#define NE      131072
#define NR      4
#define NC      1280   // [root | W0..W3] * 256

typedef __attribute__((ext_vector_type(8))) short bf16x8;
typedef __attribute__((ext_vector_type(4))) float f32x4;

__device__ __forceinline__ float sigmoidf_(float x) {
  return 1.0f / (1.0f + __expf(-x));
}

__device__ __forceinline__ void split_bf16(float v, __hip_bfloat16& hi, __hip_bfloat16& lo) {
  hi = __float2bfloat16(v);
  lo = __float2bfloat16(v - __bfloat162float(hi));
}

// ---------------- embedding concat -> x_hi/x_lo (N,384) bf16 split ----------------
__global__ void k_embed(const int* __restrict__ xi,
                        const float* __restrict__ e0, const float* __restrict__ e1,
                        const float* __restrict__ e2, const float* __restrict__ e3,
                        const float* __restrict__ e4, const float* __restrict__ e5,
                        __hip_bfloat16* __restrict__ xhi, __hip_bfloat16* __restrict__ xlo) {
  int n = blockIdx.x;
  int c = threadIdx.x;            // 0..383
  int i = c >> 6, d = c & 63;
  const float* t;
  switch (i) {
    case 0: t = e0; break; case 1: t = e1; break; case 2: t = e2; break;
    case 3: t = e3; break; case 4: t = e4; break; default: t = e5; break;
  }
  float v = t[(size_t)xi[n * 6 + i] * 64 + d];
  __hip_bfloat16 h, l; split_bf16(v, h, l);
  xhi[(size_t)n * 384 + c] = h;
  xlo[(size_t)n * 384 + c] = l;
}

// ------------- pack transposed [root|W0..W3] -> BcT_hi/lo (1280, K) bf16 -------------
__global__ void k_pack_t(const float* __restrict__ root, const float* __restrict__ W,
                         __hip_bfloat16* __restrict__ bhi, __hip_bfloat16* __restrict__ blo,
                         int K) {
  int k = blockIdx.x, seg = blockIdx.y, c = threadIdx.x;
  float v = (seg == 0) ? root[(size_t)k * 256 + c]
                       : W[((size_t)(seg - 1) * K + k) * 256 + c];
  int n = seg * 256 + c;
  __hip_bfloat16 h, l; split_bf16(v, h, l);
  bhi[(size_t)n * K + k] = h;
  blo[(size_t)n * K + k] = l;
}

// ---------------- split-bf16 MFMA GEMM: C(M,Nc) = A(M,K) @ B(Nc,K)^T ----------------
// A,B row-major with K contiguous. 128x128 tile, 4 waves, wave = 32 rows x 128 cols.
// 3-product split: hi*hi + hi*lo + lo*hi (f32 accumulate). ACT=1 -> sigmoid epilogue.
template<int ACT>
__global__ __launch_bounds__(256) void k_mfma_nt(
    const __hip_bfloat16* __restrict__ Ahi, const __hip_bfloat16* __restrict__ Alo,
    const __hip_bfloat16* __restrict__ Bhi, const __hip_bfloat16* __restrict__ Blo,
    float* __restrict__ C, int M, int Nc, int K) {
  const int tid = threadIdx.x;
  const int w = tid >> 6, l = tid & 63;
  const int bm = blockIdx.y * 128, bn = blockIdx.x * 128;
  const int lrow = l & 15, lk = (l >> 4) * 8;

  const __hip_bfloat16* aH = Ahi + (size_t)(bm + w * 32 + lrow) * K + lk;
  const __hip_bfloat16* aL = Alo + (size_t)(bm + w * 32 + lrow) * K + lk;
  const __hip_bfloat16* bH = Bhi + (size_t)(bn + lrow) * K + lk;
  const __hip_bfloat16* bL = Blo + (size_t)(bn + lrow) * K + lk;

  f32x4 acc[2][8] = {};
  for (int k0 = 0; k0 < K; k0 += 32) {
    bf16x8 a_h0 = *(const bf16x8*)(aH + k0);
    bf16x8 a_h1 = *(const bf16x8*)(aH + (size_t)16 * K + k0);
    bf16x8 a_l0 = *(const bf16x8*)(aL + k0);
    bf16x8 a_l1 = *(const bf16x8*)(aL + (size_t)16 * K + k0);
#pragma unroll
    for (int n = 0; n < 8; ++n) {
      bf16x8 b_h = *(const bf16x8*)(bH + (size_t)n * 16 * K + k0);
      bf16x8 b_l = *(const bf16x8*)(bL + (size_t)n * 16 * K + k0);
      acc[0][n] = __builtin_amdgcn_mfma_f32_16x16x32_bf16(a_h0, b_h, acc[0][n], 0, 0, 0);
      acc[1][n] = __builtin_amdgcn_mfma_f32_16x16x32_bf16(a_h1, b_h, acc[1][n], 0, 0, 0);
      acc[0][n] = __builtin_amdgcn_mfma_f32_16x16x32_bf16(a_l0, b_h, acc[0][n], 0, 0, 0);
      acc[1][n] = __builtin_amdgcn_mfma_f32_16x16x32_bf16(a_l1, b_h, acc[1][n], 0, 0, 0);
      acc[0][n] = __builtin_amdgcn_mfma_f32_16x16x32_bf16(a_h0, b_l, acc[0][n], 0, 0, 0);
      acc[1][n] = __builtin_amdgcn_mfma_f32_16x16x32_bf16(a_h1, b_l, acc[1][n], 0, 0, 0);
    }
  }
  const int crow = (l >> 4) * 4, ccol = l & 15;
#pragma unroll
  for (int m = 0; m < 2; ++m)
#pragma unroll
    for (int n = 0; n < 8; ++n) {
      float* cp = C + (size_t)(bm + w * 32 + m * 16 + crow) * Nc + bn + n * 16 + ccol;
#pragma unroll
      for (int r = 0; r < 4; ++r) {
        float v = acc[m][n][r];
        if (ACT) v = sigmoidf_(v);
        cp[(size_t)r * Nc] = v;
      }
    }
}

// ---------------- zero helpers ----------------
__global__ void k_zerof4(float4* __restrict__ p, size_t n4) {
  size_t i = (size_t)blockIdx.x * blockDim.x + threadIdx.x;
  size_t stride = (size_t)gridDim.x * blockDim.x;
  float4 z = make_float4(0.f, 0.f, 0.f, 0.f);
  for (; i < n4; i += stride) p[i] = z;
}
__global__ void k_zero_i(int* __restrict__ p, int n) {
  int i = blockIdx.x * 256 + threadIdx.x;
  if (i < n) p[i] = 0;
}

// ---------------- CSR build (by dst) ----------------
__global__ void k_count(const int* __restrict__ dst, int* __restrict__ deg) {
  int e = blockIdx.x * 256 + threadIdx.x;
  if (e < NE) atomicAdd(&deg[dst[e]], 1);
}

__global__ __launch_bounds__(1024) void k_scan(const int* __restrict__ deg,
                                               int* __restrict__ off) {
  __shared__ int s[1024];
  int t = threadIdx.x;
  int v[8];
  int run = 0;
#pragma unroll
  for (int i = 0; i < 8; ++i) {
    int tmp = deg[t * 8 + i];
    v[i] = run; run += tmp;
  }
  s[t] = run;
  __syncthreads();
  for (int ofs = 1; ofs < 1024; ofs <<= 1) {
    int x = (t >= ofs) ? s[t - ofs] : 0;
    __syncthreads();
    s[t] += x;
    __syncthreads();
  }
  int base = (t > 0) ? s[t - 1] : 0;
#pragma unroll
  for (int i = 0; i < 8; ++i) off[t * 8 + i] = base + v[i];
  if (t == 1023) off[8192] = base + run;
}

__global__ void k_fill(const int* __restrict__ src, const int* __restrict__ dst,
                       const int* __restrict__ et, const int* __restrict__ off,
                       int* __restrict__ cursor, int* __restrict__ csr) {
  int e = blockIdx.x * 256 + threadIdx.x;
  if (e < NE) {
    int d = dst[e];
    int pos = atomicAdd(&cursor[d], 1);
    csr[off[d] + pos] = (src[e] << 2) | et[e];
  }
}

// -------- combine: out = sigmoid(root + b + sum_r mean_r(neighbors)), CSR gather --------
// LAYER 1 -> h1 hi/lo bf16 split; LAYER 2 -> mu/logvar f32 (d_out)
template<int LAYER>
__global__ __launch_bounds__(256) void k_combine(
    const float* __restrict__ hall, const float* __restrict__ bias,
    const int* __restrict__ off, const int* __restrict__ csr,
    __hip_bfloat16* __restrict__ h_hi, __hip_bfloat16* __restrict__ h_lo,
    float* __restrict__ muo, float* __restrict__ lvo) {
  int n = blockIdx.x, c = threadIdx.x;
  int beg = off[n], end = off[n + 1];
  float a0 = 0.f, a1 = 0.f, a2 = 0.f, a3 = 0.f;
  int c0 = 0, c1 = 0, c2 = 0, c3 = 0;
  for (int i = beg; i < end; ++i) {
    int p = csr[i];                 // wave-uniform
    int r = p & 3;
    size_t s = (size_t)(p >> 2);
    float v = hall[s * NC + 256 + (size_t)r * 256 + c];
    if      (r == 0) { a0 += v; ++c0; }
    else if (r == 1) { a1 += v; ++c1; }
    else if (r == 2) { a2 += v; ++c2; }
    else             { a3 += v; ++c3; }
  }
  float v = hall[(size_t)n * NC + c] + bias[c]
          + a0 / (float)max(c0, 1) + a1 / (float)max(c1, 1)
          + a2 / (float)max(c2, 1) + a3 / (float)max(c3, 1);
  float sg = sigmoidf_(v);
  if (LAYER == 1) {
    __hip_bfloat16 h, l; split_bf16(sg, h, l);
    h_hi[(size_t)n * 256 + c] = h;
    h_lo[(size_t)n * 256 + c] = l;
  } else {
    if (c < 128) muo[(size_t)n * 128 + c] = sg;
    else         lvo[(size_t)n * 128 + (c - 128)] = sg;
  }
}

// ---------------- JAX threefry2x32 (partitionable) -> eps -> Z hi/lo ----------------
__device__ __forceinline__ float bits_to_normal(unsigned bits) {
  float f = __uint_as_float((bits >> 9) | 0x3f800000u) - 1.0f;  // [0,1)
  const float lo = -0.99999994f;  // nextafter(-1,0) f32
  float u = __fadd_rn(__fmul_rn(f, 2.0f), lo);
  u = fmaxf(lo, u);
  float w = -log1pf(-u * u);
  float p;
  if (w < 5.0f) {
    w = w - 2.5f;
    p = 2.81022636e-08f;
    p = fmaf(p, w, 3.43273939e-07f);
    p = fmaf(p, w, -3.5233877e-06f);
    p = fmaf(p, w, -4.39150654e-06f);
    p = fmaf(p, w, 0.00021858087f);
    p = fmaf(p, w, -0.00125372503f);
    p = fmaf(p, w, -0.00417768164f);
    p = fmaf(p, w, 0.246640727f);
    p = fmaf(p, w, 1.50140941f);
  } else {
    w = sqrtf(w) - 3.0f;
    p = -0.000200214257f;
    p = fmaf(p, w, 0.000100950558f);
    p = fmaf(p, w, 0.00134934322f);
    p = fmaf(p, w, -0.00367342844f);
    p = fmaf(p, w, 0.00573950773f);
    p = fmaf(p, w, -0.0076224613f);
    p = fmaf(p, w, 0.00943887047f);
    p = fmaf(p, w, 1.00167406f);
    p = fmaf(p, w, 2.83297682f);
  }
  return 1.41421356f * (p * u);   // sqrt(2) * erfinv(u)
}

__global__ void k_z(const float* __restrict__ mu, const float* __restrict__ lv,
                    __hip_bfloat16* __restrict__ zhi, __hip_bfloat16* __restrict__ zlo) {
  unsigned j = blockIdx.x * 256 + threadIdx.x;  // 0 .. N*128-1
  const unsigned ks0 = 0u, ks1 = 42u, ks2 = 0x1BD11BDAu ^ 0u ^ 42u;
  unsigned x0 = 0u + ks0;
  unsigned x1 = j + ks1;
#define RND(r) { x0 += x1; x1 = (x1 << r) | (x1 >> (32 - r)); x1 ^= x0; }
  RND(13) RND(15) RND(26) RND(6)  x0 += ks1; x1 += ks2 + 1u;
  RND(17) RND(29) RND(16) RND(24) x0 += ks2; x1 += ks0 + 2u;
  RND(13) RND(15) RND(26) RND(6)  x0 += ks0; x1 += ks1 + 3u;
  RND(17) RND(29) RND(16) RND(24) x0 += ks1; x1 += ks2 + 4u;
  RND(13) RND(15) RND(26) RND(6)  x0 += ks2; x1 += ks0 + 5u;
#undef RND
  unsigned bits = x0 ^ x1;
  float e = bits_to_normal(bits);
  float z = fmaf(e, __expf(0.5f * lv[j]), mu[j]);
  __hip_bfloat16 h, l; split_bf16(z, h, l);
  zhi[j] = h; zlo[j] = l;
}

// ---------------- A scatter ----------------
__global__ void k_scatterA(const int* __restrict__ src, const int* __restrict__ dst,
                           float* __restrict__ A) {
  int e = blockIdx.x * 256 + threadIdx.x;
  if (e < NE) A[(size_t)src[e] * N_NODES + dst[e]] = 1.0f;
}

extern "C" void kernel_launch(void* const* d_in, const int* in_sizes, int n_in,
                              void* d_out, int out_size, void* d_ws, size_t ws_size,
                              hipStream_t stream) {
  const int* x    = (const int*)d_in[0];
  const int* ei   = (const int*)d_in[1];
  const int* src  = ei;
  const int* dst  = ei + NE;
  const int* et   = (const int*)d_in[2];
  const float* e0 = (const float*)d_in[3];
  const float* e1 = (const float*)d_in[4];
  const float* e2 = (const float*)d_in[5];
  const float* e3 = (const float*)d_in[6];
  const float* e4 = (const float*)d_in[7];
  const float* e5 = (const float*)d_in[8];
  const float* W1 = (const float*)d_in[9];
  const float* r1 = (const float*)d_in[10];
  const float* b1 = (const float*)d_in[11];
  const float* W2 = (const float*)d_in[12];
  const float* r2 = (const float*)d_in[13];
  const float* b2 = (const float*)d_in[14];

  float* out  = (float*)d_out;
  float* A    = out;                                    // N*N
  float* Ahat = out + (size_t)N_NODES * N_NODES;        // N*N
  float* muo  = Ahat + (size_t)N_NODES * N_NODES;       // N*128
  float* lvo  = muo + (size_t)N_NODES * 128;            // N*128

  char* wp = (char*)d_ws;
  auto carve = [&](size_t bytes) { char* r = wp; wp += (bytes + 255) & ~(size_t)255; return r; };
  __hip_bfloat16* xhi  = (__hip_bfloat16*)carve((size_t)8192 * 384 * 2);
  __hip_bfloat16* xlo  = (__hip_bfloat16*)carve((size_t)8192 * 384 * 2);
  __hip_bfloat16* bthi = (__hip_bfloat16*)carve((size_t)NC * 384 * 2);
  __hip_bfloat16* btlo = (__hip_bfloat16*)carve((size_t)NC * 384 * 2);
  float*          hall = (float*)carve((size_t)8192 * NC * 4);
  __hip_bfloat16* h1hi = (__hip_bfloat16*)carve((size_t)8192 * 256 * 2);
  __hip_bfloat16* h1lo = (__hip_bfloat16*)carve((size_t)8192 * 256 * 2);
  __hip_bfloat16* zhi  = (__hip_bfloat16*)carve((size_t)8192 * 128 * 2);
  __hip_bfloat16* zlo  = (__hip_bfloat16*)carve((size_t)8192 * 128 * 2);
  int*            deg  = (int*)carve((size_t)8192 * 4);
  int*            cur  = (int*)carve((size_t)8192 * 4);
  int*            off  = (int*)carve((size_t)8193 * 4);
  int*            csr  = (int*)carve((size_t)NE * 4);

  // ---- CSR build (shared by both layers) ----
  k_zero_i<<<64, 256, 0, stream>>>(deg, 16384);        // deg + cur (contiguous)
  k_count<<<NE / 256, 256, 0, stream>>>(dst, deg);
  k_scan<<<1, 1024, 0, stream>>>(deg, off);
  k_fill<<<NE / 256, 256, 0, stream>>>(src, dst, et, off, cur, csr);

  // ---- layer 1 ----
  k_embed<<<8192, 384, 0, stream>>>(x, e0, e1, e2, e3, e4, e5, xhi, xlo);
  k_pack_t<<<dim3(384, 5), 256, 0, stream>>>(r1, W1, bthi, btlo, 384);
  k_mfma_nt<0><<<dim3(NC / 128, 64), 256, 0, stream>>>(xhi, xlo, bthi, btlo, hall,
                                                       8192, NC, 384);
  k_combine<1><<<8192, 256, 0, stream>>>(hall, b1, off, csr, h1hi, h1lo, nullptr, nullptr);

  // ---- layer 2 ----
  k_pack_t<<<dim3(256, 5), 256, 0, stream>>>(r2, W2, bthi, btlo, 256);
  k_mfma_nt<0><<<dim3(NC / 128, 64), 256, 0, stream>>>(h1hi, h1lo, bthi, btlo, hall,
                                                       8192, NC, 256);
  k_combine<2><<<8192, 256, 0, stream>>>(hall, b2, off, csr, nullptr, nullptr, muo, lvo);

  // ---- reparametrize -> Z (bf16 split) ----
  k_z<<<4096, 256, 0, stream>>>(muo, lvo, zhi, zlo);

  // ---- A = scatter(1.0) ----
  k_zerof4<<<8192, 256, 0, stream>>>((float4*)A, (size_t)N_NODES * N_NODES / 4);
  k_scatterA<<<NE / 256, 256, 0, stream>>>(src, dst, A);

  // ---- A_hat = sigmoid(Z @ Z^T) ----
  k_mfma_nt<1><<<dim3(64, 64), 256, 0, stream>>>(zhi, zlo, zhi, zlo, Ahat,
                                                 8192, 8192, 128);
}

// Round 3
// 356.703 us; speedup vs baseline: 2.1138x; 1.3977x over previous
//
#include <hip/hip_runtime.h>
#include <hip/hip_bf16.h>
#include <cstdint>
#include <cstddef>

#define N_NODES 8192
#define NE      131072
#define NR      4
#define NC      1280   // [root | W0..W3] * 256

typedef __attribute__((ext_vector_type(8))) short bf16x8;
typedef __attribute__((ext_vector_type(4))) float f32x4;

__device__ __forceinline__ float sigmoidf_(float x) {
  return 1.0f / (1.0f + __expf(-x));
}

__device__ __forceinline__ void split_bf16(float v, __hip_bfloat16& hi, __hip_bfloat16& lo) {
  hi = __float2bfloat16(v);
  lo = __float2bfloat16(v - __bfloat162float(hi));
}

// ---------------- embedding concat -> x_hi (N,384) bf16 (hi only: layer1 is 1-product) ----
__global__ void k_embed(const int* __restrict__ xi,
                        const float* __restrict__ e0, const float* __restrict__ e1,
                        const float* __restrict__ e2, const float* __restrict__ e3,
                        const float* __restrict__ e4, const float* __restrict__ e5,
                        __hip_bfloat16* __restrict__ xhi) {
  int n = blockIdx.x;
  int c = threadIdx.x;            // 0..383
  int i = c >> 6, d = c & 63;
  const float* t;
  switch (i) {
    case 0: t = e0; break; case 1: t = e1; break; case 2: t = e2; break;
    case 3: t = e3; break; case 4: t = e4; break; default: t = e5; break;
  }
  float v = t[(size_t)xi[n * 6 + i] * 64 + d];
  xhi[(size_t)n * 384 + c] = __float2bfloat16(v);
}

// ------------- pack transposed [root|W0..W3] -> BcT (1280, K) bf16 (optionally split) ----
template<int LO>
__global__ void k_pack_t(const float* __restrict__ root, const float* __restrict__ W,
                         __hip_bfloat16* __restrict__ bhi, __hip_bfloat16* __restrict__ blo,
                         int K) {
  int k = blockIdx.x, seg = blockIdx.y, c = threadIdx.x;
  float v = (seg == 0) ? root[(size_t)k * 256 + c]
                       : W[((size_t)(seg - 1) * K + k) * 256 + c];
  int n = seg * 256 + c;
  if (LO) {
    __hip_bfloat16 h, l; split_bf16(v, h, l);
    bhi[(size_t)n * K + k] = h;
    blo[(size_t)n * K + k] = l;
  } else {
    bhi[(size_t)n * K + k] = __float2bfloat16(v);
  }
}

// ============ unified MFMA GEMM: C(M,Nc) = A(M,K) @ B(Nc,K)^T, bf16, f32-acc ============
// A,B row-major K-contiguous. 128x128 C-tile, 4 waves (wave = 32 rows x 128 cols).
// B panel staged in LDS per 128-K chunk, XOR-swizzled (involution on byte bits 4-6 by row&7).
// SPLIT3: 3-product hi/lo split. ACT: sigmoid. SYM: triangular grid + mirror write (Nc==M).
template<int SPLIT3, int ACT, int SYM>
__global__ __launch_bounds__(256) void k_gemm2(
    const ushort* __restrict__ Ahi, const ushort* __restrict__ Alo,
    const ushort* __restrict__ Bhi, const ushort* __restrict__ Blo,
    float* __restrict__ C, int Nc, int K) {
  __shared__ ushort Bs[(SPLIT3 ? 2 : 1) * 128 * 128];
  ushort* BsH = Bs;
  ushort* BsL = Bs + 128 * 128;

  const int tid = threadIdx.x;
  const int w = tid >> 6, l = tid & 63;
  const int lrow = l & 15, lk8 = (l >> 4) * 8;

  int brow, bcol, p = 0, q = 0;
  if (SYM) {
    int b = blockIdx.x;
    q = (int)((sqrtf(8.f * (float)b + 1.f) - 1.f) * 0.5f);
    while ((q + 1) * (q + 2) / 2 <= b) ++q;
    while (q * (q + 1) / 2 > b) --q;
    p = b - q * (q + 1) / 2;          // p <= q
    brow = p * 128; bcol = q * 128;
  } else {
    brow = blockIdx.y * 128; bcol = blockIdx.x * 128;
  }

  f32x4 acc[2][8] = {};
  const size_t arow0 = (size_t)(brow + w * 32 + lrow) * K + lk8;
  const size_t arow1 = arow0 + (size_t)16 * K;

  for (int kc = 0; kc < K; kc += 128) {
    // ---- A fragments for this chunk (each element read exactly once; 64B-granule) ----
    bf16x8 aH[4][2], aL[4][2];
#pragma unroll
    for (int kk = 0; kk < 4; ++kk) {
      aH[kk][0] = *(const bf16x8*)(Ahi + arow0 + kc + kk * 32);
      aH[kk][1] = *(const bf16x8*)(Ahi + arow1 + kc + kk * 32);
      if (SPLIT3) {
        aL[kk][0] = *(const bf16x8*)(Alo + arow0 + kc + kk * 32);
        aL[kk][1] = *(const bf16x8*)(Alo + arow1 + kc + kk * 32);
      }
    }
    if (kc) __syncthreads();          // LDS reuse guard
    // ---- stage B panel [128 rows][128 k] to LDS, swizzled source -> linear dest ----
#pragma unroll
    for (int it = 0; it < 8; ++it) {
      int o = (it * 256 + tid) * 16;                // byte offset in 32KB tile
      int row = o >> 8, sb = o & 255;
      int se = (sb ^ ((row & 7) << 4)) >> 1;        // swizzled element-in-row
      size_t g = (size_t)(bcol + row) * K + kc + se;
      *(uint4*)((char*)BsH + o) = *(const uint4*)(Bhi + g);
      if (SPLIT3) *(uint4*)((char*)BsL + o) = *(const uint4*)(Blo + g);
    }
    __syncthreads();
    // ---- MFMA over the chunk ----
#pragma unroll
    for (int kk = 0; kk < 4; ++kk) {
#pragma unroll
      for (int n = 0; n < 8; ++n) {
        int row_t = n * 16 + lrow;
        int addr = row_t * 256 + ((kk * 64 + (l >> 4) * 16) ^ ((row_t & 7) << 4));
        bf16x8 b_h = *(const bf16x8*)((const char*)BsH + addr);
        acc[0][n] = __builtin_amdgcn_mfma_f32_16x16x32_bf16(aH[kk][0], b_h, acc[0][n], 0, 0, 0);
        acc[1][n] = __builtin_amdgcn_mfma_f32_16x16x32_bf16(aH[kk][1], b_h, acc[1][n], 0, 0, 0);
        if (SPLIT3) {
          bf16x8 b_l = *(const bf16x8*)((const char*)BsL + addr);
          acc[0][n] = __builtin_amdgcn_mfma_f32_16x16x32_bf16(aL[kk][0], b_h, acc[0][n], 0, 0, 0);
          acc[1][n] = __builtin_amdgcn_mfma_f32_16x16x32_bf16(aL[kk][1], b_h, acc[1][n], 0, 0, 0);
          acc[0][n] = __builtin_amdgcn_mfma_f32_16x16x32_bf16(aH[kk][0], b_l, acc[0][n], 0, 0, 0);
          acc[1][n] = __builtin_amdgcn_mfma_f32_16x16x32_bf16(aH[kk][1], b_l, acc[1][n], 0, 0, 0);
        }
      }
    }
  }

  // ---- epilogue ----
  const int crow = (l >> 4) * 4, ccol = l & 15;
#pragma unroll
  for (int m = 0; m < 2; ++m)
#pragma unroll
    for (int n = 0; n < 8; ++n) {
      float v[4];
#pragma unroll
      for (int r = 0; r < 4; ++r) {
        float t = acc[m][n][r];
        v[r] = ACT ? sigmoidf_(t) : t;
      }
      int rloc = w * 32 + m * 16 + crow;      // row within tile (of the 4-reg group)
      int cloc = n * 16 + ccol;               // col within tile
      float* cp = C + (size_t)(brow + rloc) * Nc + bcol + cloc;
#pragma unroll
      for (int r = 0; r < 4; ++r) cp[(size_t)r * Nc] = v[r];
      if (SYM && p != q) {
        // mirror tile: row' = bcol + cloc, cols' = brow + rloc .. +3 (contiguous float4)
        float* mp = C + (size_t)(bcol + cloc) * Nc + brow + rloc;
        *(float4*)mp = make_float4(v[0], v[1], v[2], v[3]);
      }
    }
}

// ---------------- zero helpers ----------------
__global__ void k_zerof4(float4* __restrict__ p, size_t n4) {
  size_t i = (size_t)blockIdx.x * blockDim.x + threadIdx.x;
  size_t stride = (size_t)gridDim.x * blockDim.x;
  float4 z = make_float4(0.f, 0.f, 0.f, 0.f);
  for (; i < n4; i += stride) p[i] = z;
}
__global__ void k_zero_i(int* __restrict__ p, int n) {
  int i = blockIdx.x * 256 + threadIdx.x;
  if (i < n) p[i] = 0;
}

// ---------------- CSR build (by dst) ----------------
__global__ void k_count(const int* __restrict__ dst, int* __restrict__ deg) {
  int e = blockIdx.x * 256 + threadIdx.x;
  if (e < NE) atomicAdd(&deg[dst[e]], 1);
}

__global__ __launch_bounds__(1024) void k_scan(const int* __restrict__ deg,
                                               int* __restrict__ off) {
  __shared__ int s[1024];
  int t = threadIdx.x;
  int v[8];
  int run = 0;
#pragma unroll
  for (int i = 0; i < 8; ++i) {
    int tmp = deg[t * 8 + i];
    v[i] = run; run += tmp;
  }
  s[t] = run;
  __syncthreads();
  for (int ofs = 1; ofs < 1024; ofs <<= 1) {
    int x = (t >= ofs) ? s[t - ofs] : 0;
    __syncthreads();
    s[t] += x;
    __syncthreads();
  }
  int base = (t > 0) ? s[t - 1] : 0;
#pragma unroll
  for (int i = 0; i < 8; ++i) off[t * 8 + i] = base + v[i];
  if (t == 1023) off[8192] = base + run;
}

__global__ void k_fill(const int* __restrict__ src, const int* __restrict__ dst,
                       const int* __restrict__ et, const int* __restrict__ off,
                       int* __restrict__ cursor, int* __restrict__ csr) {
  int e = blockIdx.x * 256 + threadIdx.x;
  if (e < NE) {
    int d = dst[e];
    int pos = atomicAdd(&cursor[d], 1);
    csr[off[d] + pos] = (src[e] << 2) | et[e];
  }
}

// -------- combine: out = sigmoid(root + b + sum_r mean_r(neighbors)), CSR gather --------
// csr chunk prefetched into LDS (parallel), then unroll-4 independent hall gathers.
template<int LAYER>
__global__ __launch_bounds__(256) void k_combine(
    const float* __restrict__ hall, const float* __restrict__ bias,
    const int* __restrict__ off, const int* __restrict__ csr,
    __hip_bfloat16* __restrict__ h_hi, __hip_bfloat16* __restrict__ h_lo,
    float* __restrict__ muo, float* __restrict__ lvo) {
  __shared__ int sc[64];
  int n = blockIdx.x, c = threadIdx.x;
  int beg = off[n], end = off[n + 1];
  float a0 = 0.f, a1 = 0.f, a2 = 0.f, a3 = 0.f;
  int c0 = 0, c1 = 0, c2 = 0, c3 = 0;
  for (int base = beg; base < end; base += 64) {
    int mcnt = min(64, end - base);
    if (c < 64 && base + c < end) sc[c] = csr[base + c];
    __syncthreads();
    int i = 0;
    for (; i + 4 <= mcnt; i += 4) {
      int p0 = sc[i], p1 = sc[i + 1], p2 = sc[i + 2], p3 = sc[i + 3];
      float v0 = hall[(size_t)(p0 >> 2) * NC + 256 + (size_t)(p0 & 3) * 256 + c];
      float v1 = hall[(size_t)(p1 >> 2) * NC + 256 + (size_t)(p1 & 3) * 256 + c];
      float v2 = hall[(size_t)(p2 >> 2) * NC + 256 + (size_t)(p2 & 3) * 256 + c];
      float v3 = hall[(size_t)(p3 >> 2) * NC + 256 + (size_t)(p3 & 3) * 256 + c];
      int r;
      r = p0 & 3; if (r == 0) { a0 += v0; ++c0; } else if (r == 1) { a1 += v0; ++c1; }
                  else if (r == 2) { a2 += v0; ++c2; } else { a3 += v0; ++c3; }
      r = p1 & 3; if (r == 0) { a0 += v1; ++c0; } else if (r == 1) { a1 += v1; ++c1; }
                  else if (r == 2) { a2 += v1; ++c2; } else { a3 += v1; ++c3; }
      r = p2 & 3; if (r == 0) { a0 += v2; ++c0; } else if (r == 1) { a1 += v2; ++c1; }
                  else if (r == 2) { a2 += v2; ++c2; } else { a3 += v2; ++c3; }
      r = p3 & 3; if (r == 0) { a0 += v3; ++c0; } else if (r == 1) { a1 += v3; ++c1; }
                  else if (r == 2) { a2 += v3; ++c2; } else { a3 += v3; ++c3; }
    }
    for (; i < mcnt; ++i) {
      int pp = sc[i];
      int r = pp & 3;
      float v = hall[(size_t)(pp >> 2) * NC + 256 + (size_t)r * 256 + c];
      if (r == 0) { a0 += v; ++c0; } else if (r == 1) { a1 += v; ++c1; }
      else if (r == 2) { a2 += v; ++c2; } else { a3 += v; ++c3; }
    }
    __syncthreads();
  }
  float v = hall[(size_t)n * NC + c] + bias[c]
          + a0 / (float)max(c0, 1) + a1 / (float)max(c1, 1)
          + a2 / (float)max(c2, 1) + a3 / (float)max(c3, 1);
  float sg = sigmoidf_(v);
  if (LAYER == 1) {
    __hip_bfloat16 h, l; split_bf16(sg, h, l);
    h_hi[(size_t)n * 256 + c] = h;
    h_lo[(size_t)n * 256 + c] = l;
  } else {
    if (c < 128) muo[(size_t)n * 128 + c] = sg;
    else         lvo[(size_t)n * 128 + (c - 128)] = sg;
  }
}

// ---------------- JAX threefry2x32 (partitionable) -> eps -> Z hi/lo ----------------
__device__ __forceinline__ float bits_to_normal(unsigned bits) {
  float f = __uint_as_float((bits >> 9) | 0x3f800000u) - 1.0f;  // [0,1)
  const float lo = -0.99999994f;  // nextafter(-1,0) f32
  float u = __fadd_rn(__fmul_rn(f, 2.0f), lo);
  u = fmaxf(lo, u);
  float w = -log1pf(-u * u);
  float p;
  if (w < 5.0f) {
    w = w - 2.5f;
    p = 2.81022636e-08f;
    p = fmaf(p, w, 3.43273939e-07f);
    p = fmaf(p, w, -3.5233877e-06f);
    p = fmaf(p, w, -4.39150654e-06f);
    p = fmaf(p, w, 0.00021858087f);
    p = fmaf(p, w, -0.00125372503f);
    p = fmaf(p, w, -0.00417768164f);
    p = fmaf(p, w, 0.246640727f);
    p = fmaf(p, w, 1.50140941f);
  } else {
    w = sqrtf(w) - 3.0f;
    p = -0.000200214257f;
    p = fmaf(p, w, 0.000100950558f);
    p = fmaf(p, w, 0.00134934322f);
    p = fmaf(p, w, -0.00367342844f);
    p = fmaf(p, w, 0.00573950773f);
    p = fmaf(p, w, -0.0076224613f);
    p = fmaf(p, w, 0.00943887047f);
    p = fmaf(p, w, 1.00167406f);
    p = fmaf(p, w, 2.83297682f);
  }
  return 1.41421356f * (p * u);   // sqrt(2) * erfinv(u)
}

__global__ void k_z(const float* __restrict__ mu, const float* __restrict__ lv,
                    __hip_bfloat16* __restrict__ zhi, __hip_bfloat16* __restrict__ zlo) {
  unsigned j = blockIdx.x * 256 + threadIdx.x;  // 0 .. N*128-1
  const unsigned ks0 = 0u, ks1 = 42u, ks2 = 0x1BD11BDAu ^ 0u ^ 42u;
  unsigned x0 = 0u + ks0;
  unsigned x1 = j + ks1;
#define RND(r) { x0 += x1; x1 = (x1 << r) | (x1 >> (32 - r)); x1 ^= x0; }
  RND(13) RND(15) RND(26) RND(6)  x0 += ks1; x1 += ks2 + 1u;
  RND(17) RND(29) RND(16) RND(24) x0 += ks2; x1 += ks0 + 2u;
  RND(13) RND(15) RND(26) RND(6)  x0 += ks0; x1 += ks1 + 3u;
  RND(17) RND(29) RND(16) RND(24) x0 += ks1; x1 += ks2 + 4u;
  RND(13) RND(15) RND(26) RND(6)  x0 += ks2; x1 += ks0 + 5u;
#undef RND
  unsigned bits = x0 ^ x1;
  float e = bits_to_normal(bits);
  float z = fmaf(e, __expf(0.5f * lv[j]), mu[j]);
  __hip_bfloat16 h, l; split_bf16(z, h, l);
  zhi[j] = h; zlo[j] = l;
}

// ---------------- A scatter ----------------
__global__ void k_scatterA(const int* __restrict__ src, const int* __restrict__ dst,
                           float* __restrict__ A) {
  int e = blockIdx.x * 256 + threadIdx.x;
  if (e < NE) A[(size_t)src[e] * N_NODES + dst[e]] = 1.0f;
}

extern "C" void kernel_launch(void* const* d_in, const int* in_sizes, int n_in,
                              void* d_out, int out_size, void* d_ws, size_t ws_size,
                              hipStream_t stream) {
  const int* x    = (const int*)d_in[0];
  const int* ei   = (const int*)d_in[1];
  const int* src  = ei;
  const int* dst  = ei + NE;
  const int* et   = (const int*)d_in[2];
  const float* e0 = (const float*)d_in[3];
  const float* e1 = (const float*)d_in[4];
  const float* e2 = (const float*)d_in[5];
  const float* e3 = (const float*)d_in[6];
  const float* e4 = (const float*)d_in[7];
  const float* e5 = (const float*)d_in[8];
  const float* W1 = (const float*)d_in[9];
  const float* r1 = (const float*)d_in[10];
  const float* b1 = (const float*)d_in[11];
  const float* W2 = (const float*)d_in[12];
  const float* r2 = (const float*)d_in[13];
  const float* b2 = (const float*)d_in[14];

  float* out  = (float*)d_out;
  float* A    = out;                                    // N*N
  float* Ahat = out + (size_t)N_NODES * N_NODES;        // N*N
  float* muo  = Ahat + (size_t)N_NODES * N_NODES;       // N*128
  float* lvo  = muo + (size_t)N_NODES * 128;            // N*128

  char* wp = (char*)d_ws;
  auto carve = [&](size_t bytes) { char* r = wp; wp += (bytes + 255) & ~(size_t)255; return r; };
  __hip_bfloat16* xhi  = (__hip_bfloat16*)carve((size_t)8192 * 384 * 2);
  __hip_bfloat16* bthi = (__hip_bfloat16*)carve((size_t)NC * 384 * 2);
  __hip_bfloat16* btlo = (__hip_bfloat16*)carve((size_t)NC * 384 * 2);
  float*          hall = (float*)carve((size_t)8192 * NC * 4);
  __hip_bfloat16* h1hi = (__hip_bfloat16*)carve((size_t)8192 * 256 * 2);
  __hip_bfloat16* h1lo = (__hip_bfloat16*)carve((size_t)8192 * 256 * 2);
  __hip_bfloat16* zhi  = (__hip_bfloat16*)carve((size_t)8192 * 128 * 2);
  __hip_bfloat16* zlo  = (__hip_bfloat16*)carve((size_t)8192 * 128 * 2);
  int*            deg  = (int*)carve((size_t)8192 * 4);
  int*            cur  = (int*)carve((size_t)8192 * 4);
  int*            off  = (int*)carve((size_t)8193 * 4);
  int*            csr  = (int*)carve((size_t)NE * 4);

  // ---- CSR build (shared by both layers) ----
  k_zero_i<<<64, 256, 0, stream>>>(deg, 16384);        // deg + cur (contiguous carve)
  k_count<<<NE / 256, 256, 0, stream>>>(dst, deg);
  k_scan<<<1, 1024, 0, stream>>>(deg, off);
  k_fill<<<NE / 256, 256, 0, stream>>>(src, dst, et, off, cur, csr);

  // ---- layer 1 (hi-only: 1 MFMA product) ----
  k_embed<<<8192, 384, 0, stream>>>(x, e0, e1, e2, e3, e4, e5, xhi);
  k_pack_t<0><<<dim3(384, 5), 256, 0, stream>>>(r1, W1, bthi, nullptr, 384);
  k_gemm2<0, 0, 0><<<dim3(NC / 128, 64), 256, 0, stream>>>(
      (const ushort*)xhi, nullptr, (const ushort*)bthi, nullptr, hall, NC, 384);
  k_combine<1><<<8192, 256, 0, stream>>>(hall, b1, off, csr, h1hi, h1lo, nullptr, nullptr);

  // ---- layer 2 (3-product split) ----
  k_pack_t<1><<<dim3(256, 5), 256, 0, stream>>>(r2, W2, bthi, btlo, 256);
  k_gemm2<1, 0, 0><<<dim3(NC / 128, 64), 256, 0, stream>>>(
      (const ushort*)h1hi, (const ushort*)h1lo, (const ushort*)bthi, (const ushort*)btlo,
      hall, NC, 256);
  k_combine<2><<<8192, 256, 0, stream>>>(hall, b2, off, csr, nullptr, nullptr, muo, lvo);

  // ---- reparametrize -> Z (bf16 split) ----
  k_z<<<4096, 256, 0, stream>>>(muo, lvo, zhi, zlo);

  // ---- A = scatter(1.0) ----
  k_zerof4<<<8192, 256, 0, stream>>>((float4*)A, (size_t)N_NODES * N_NODES / 4);
  k_scatterA<<<NE / 256, 256, 0, stream>>>(src, dst, A);

  // ---- A_hat = sigmoid(Z @ Z^T): symmetric, upper-triangle blocks + mirror ----
  k_gemm2<1, 1, 1><<<dim3(64 * 65 / 2), 256, 0, stream>>>(
      (const ushort*)zhi, (const ushort*)zlo, (const ushort*)zhi, (const ushort*)zlo,
      Ahat, N_NODES, 128);
}